// Round 5
// baseline (298.403 us; speedup 1.0000x reference)
//
#include <hip/hip_runtime.h>
#include <hip/hip_bf16.h>
#include <math.h>

#define Bn 8
#define Tn 2048
#define Cn 1024
#define Hn 64
#define BTHb ((size_t)Bn * Tn * Hn)   // elements per projected matrix (bf16)
#define WELEMS ((size_t)Hn * Cn)      // 65536 elements per W matrix

typedef __attribute__((ext_vector_type(8))) short bf16x8;
typedef __attribute__((ext_vector_type(4))) float f32x4;

static __device__ __forceinline__ unsigned short bf16rne(float f) {
    union { float f; unsigned u; } x; x.f = f;
    return (unsigned short)((x.u + 0x7FFFu + ((x.u >> 16) & 1u)) >> 16);
}

// ---------------------------------------------------------------------------
// W pre-convert: Wk|Wq|Wv fp32 -> bf16 (ws + 3*BTHb). 49152 float4s total.
// ---------------------------------------------------------------------------
__global__ __launch_bounds__(256) void wconv_kernel(
    const float* __restrict__ Wk, const float* __restrict__ Wq,
    const float* __restrict__ Wv, unsigned short* __restrict__ dst)
{
    const int g = blockIdx.x * 256 + threadIdx.x;        // 0..49151
    const float* src = (g < 16384) ? Wk : (g < 32768) ? Wq : Wv;
    const int local = g & 16383;
    const float4 f = ((const float4*)src)[local];
    ushort4 u;
    u.x = bf16rne(f.x); u.y = bf16rne(f.y);
    u.z = bf16rne(f.z); u.w = bf16rne(f.w);
    ((ushort4*)dst)[g] = u;
}

// ---------------------------------------------------------------------------
// MFMA projection v3: O[row,h] = sum_c X[row,c] * W[h,c]
// grid (256, 3); block 256 = 4 waves; 64 rows x 64 h per block.
// ZERO barriers, ZERO LDS:
//  - A-frags: lane loads its own X row (fp32, HBM) directly, converts to
//    bf16 in regs. Double-buffered across 128-col chunks.
//  - B-frags: lane loads W bf16 directly from global (L2/L3-hot; W = 128 KB,
//    re-read per wave). No barrier ever drains the vmcnt queue, so the
//    X HBM stream pipelines freely across the whole K loop.
// ---------------------------------------------------------------------------
__global__ __launch_bounds__(256, 2) void proj_kernel(
    const float* __restrict__ k, const float* __restrict__ q,
    const float* __restrict__ v,
    unsigned short* __restrict__ ws)
{
    const int which = blockIdx.y;
    const float* X = (which == 0) ? k : (which == 1) ? q : v;
    const unsigned short* Wsrc = ws + 3 * BTHb + (size_t)which * WELEMS;
    unsigned short* O = ws + (size_t)which * BTHb;

    const int tid  = threadIdx.x;
    const int wave = __builtin_amdgcn_readfirstlane(tid >> 6);
    const int lane = tid & 63;
    const int ln   = lane & 15;
    const int quad = lane >> 4;
    const int row0 = blockIdx.x * 64;

    // this lane's X row, col base quad*8
    const float* Xrow = X + (size_t)(row0 + wave * 16 + ln) * Cn + quad * 8;
    // this lane's 4 W row bases (ht*16+ln), col base quad*8
    const unsigned short* Wrow0 = Wsrc + (size_t)(0 * 16 + ln) * Cn + quad * 8;
    const unsigned short* Wrow1 = Wsrc + (size_t)(1 * 16 + ln) * Cn + quad * 8;
    const unsigned short* Wrow2 = Wsrc + (size_t)(2 * 16 + ln) * Cn + quad * 8;
    const unsigned short* Wrow3 = Wsrc + (size_t)(3 * 16 + ln) * Cn + quad * 8;

    f32x4 acc[4];
#pragma unroll
    for (int t = 0; t < 4; ++t) acc[t] = (f32x4){0.f, 0.f, 0.f, 0.f};

    float4 xA[8], xB[8];

    // prefetch chunk 0 into xA
#pragma unroll
    for (int kc = 0; kc < 4; ++kc) {
        xA[2 * kc]     = *(const float4*)(Xrow + kc * 32);
        xA[2 * kc + 1] = *(const float4*)(Xrow + kc * 32 + 4);
    }

#pragma unroll 2
    for (int ct = 0; ct < 8; ++ct) {
        float4* xcur = (ct & 1) ? xB : xA;
        float4* xnxt = (ct & 1) ? xA : xB;
        const int ctn = (ct + 1) & 7;   // wrap: keeps last prefetch in-bounds

        // convert current X chunk -> bf16 A-frags
        bf16x8 af[4];
#pragma unroll
        for (int kc = 0; kc < 4; ++kc) {
            union { bf16x8 v; unsigned short s[8]; } u;
            const float4 a = xcur[2 * kc], b = xcur[2 * kc + 1];
            u.s[0] = bf16rne(a.x); u.s[1] = bf16rne(a.y);
            u.s[2] = bf16rne(a.z); u.s[3] = bf16rne(a.w);
            u.s[4] = bf16rne(b.x); u.s[5] = bf16rne(b.y);
            u.s[6] = bf16rne(b.z); u.s[7] = bf16rne(b.w);
            af[kc] = u.v;
        }

        // prefetch next X chunk (HBM) — no barrier will ever drain these
#pragma unroll
        for (int kc = 0; kc < 4; ++kc) {
            xnxt[2 * kc]     = *(const float4*)(Xrow + ctn * 128 + kc * 32);
            xnxt[2 * kc + 1] = *(const float4*)(Xrow + ctn * 128 + kc * 32 + 4);
        }

        // B-frags direct from global (L2-hot) + MFMA
#pragma unroll
        for (int kc = 0; kc < 4; ++kc) {
            const int co = ct * 128 + kc * 32;
            const bf16x8 w0 = *(const bf16x8*)(Wrow0 + co);
            const bf16x8 w1 = *(const bf16x8*)(Wrow1 + co);
            const bf16x8 w2 = *(const bf16x8*)(Wrow2 + co);
            const bf16x8 w3 = *(const bf16x8*)(Wrow3 + co);
            acc[0] = __builtin_amdgcn_mfma_f32_16x16x32_bf16(af[kc], w0,
                                                             acc[0], 0, 0, 0);
            acc[1] = __builtin_amdgcn_mfma_f32_16x16x32_bf16(af[kc], w1,
                                                             acc[1], 0, 0, 0);
            acc[2] = __builtin_amdgcn_mfma_f32_16x16x32_bf16(af[kc], w2,
                                                             acc[2], 0, 0, 0);
            acc[3] = __builtin_amdgcn_mfma_f32_16x16x32_bf16(af[kc], w3,
                                                             acc[3], 0, 0, 0);
        }
    }

    // D layout: col=lane&15, row=quad*4+reg
#pragma unroll
    for (int ht = 0; ht < 4; ++ht)
#pragma unroll
        for (int r = 0; r < 4; ++r)
            O[(size_t)(row0 + wave * 16 + quad * 4 + r) * Hn + ht * 16 + ln] =
                bf16rne(acc[ht][r]);
}

// ---------------------------------------------------------------------------
// MFMA flash attention (unchanged — validated). grid (32, 8);
// block 256 = 4 waves; 64-row q-tile per block; 64-key tiles.
// ---------------------------------------------------------------------------
__global__ __launch_bounds__(256) void attn_kernel(
    const unsigned short* __restrict__ ws,
    const int* __restrict__ mask,
    float* __restrict__ out)
{
    const unsigned short* kh = ws;
    const unsigned short* qh = ws + BTHb;
    const unsigned short* vh = ws + 2 * BTHb;

    const int b   = blockIdx.y;
    const int qt  = blockIdx.x;
    const int tid = threadIdx.x;
    const int wave = __builtin_amdgcn_readfirstlane(tid >> 6);
    const int lane = tid & 63;
    const int ln   = lane & 15;
    const int quad = lane >> 4;

    __shared__ unsigned short Ks[64][72];   // [kpos][dim]
    __shared__ unsigned short Vt[64][72];   // [dim][kpos]
    __shared__ unsigned short Ps[64][72];   // [q-row local][kpos]
    __shared__ int Msk[64];

    const int wrb = qt * 64 + wave * 16;

    bf16x8 qa[2];
#pragma unroll
    for (int kc = 0; kc < 2; ++kc)
        qa[kc] = *(const bf16x8*)(qh + ((size_t)b * Tn + wrb + ln) * Hn
                                     + kc * 32 + quad * 8);

    f32x4 oacc[4];
#pragma unroll
    for (int t = 0; t < 4; ++t) oacc[t] = (f32x4){0.f, 0.f, 0.f, 0.f};
    float mrow[4] = {-1e30f, -1e30f, -1e30f, -1e30f};
    float lrow[4] = {0.f, 0.f, 0.f, 0.f};

    const int krow = tid >> 2, kseg = tid & 3;
    const int vcol = tid & 63, vseg = tid >> 6;

    uint4 kreg[2], vreg[2];
    int mreg = 0;
    {
        const unsigned short* kp =
            kh + ((size_t)b * Tn + krow) * Hn + kseg * 16;
        kreg[0] = *(const uint4*)kp;
        kreg[1] = *(const uint4*)(kp + 8);
        const unsigned short* vp =
            vh + ((size_t)b * Tn + vcol) * Hn + vseg * 16;
        vreg[0] = *(const uint4*)vp;
        vreg[1] = *(const uint4*)(vp + 8);
        if (tid < 64) mreg = mask[(size_t)b * Tn + tid];
    }

    for (int j = 0; j <= qt; ++j) {
        __syncthreads();
        *(uint4*)&Ks[krow][kseg * 16]     = kreg[0];
        *(uint4*)&Ks[krow][kseg * 16 + 8] = kreg[1];
        {
            const unsigned short* vs = (const unsigned short*)vreg;
#pragma unroll
            for (int jj = 0; jj < 16; ++jj)
                Vt[vseg * 16 + jj][vcol] = vs[jj];
        }
        if (tid < 64) Msk[tid] = mreg;
        __syncthreads();

        if (j < qt) {
            const unsigned short* kp =
                kh + ((size_t)b * Tn + (j + 1) * 64 + krow) * Hn + kseg * 16;
            kreg[0] = *(const uint4*)kp;
            kreg[1] = *(const uint4*)(kp + 8);
            const unsigned short* vp =
                vh + ((size_t)b * Tn + (j + 1) * 64 + vcol) * Hn + vseg * 16;
            vreg[0] = *(const uint4*)vp;
            vreg[1] = *(const uint4*)(vp + 8);
            if (tid < 64) mreg = mask[(size_t)b * Tn + (j + 1) * 64 + tid];
        }

        f32x4 sacc[4];
#pragma unroll
        for (int t = 0; t < 4; ++t) sacc[t] = (f32x4){0.f, 0.f, 0.f, 0.f};
#pragma unroll
        for (int kc = 0; kc < 2; ++kc) {
#pragma unroll
            for (int nt = 0; nt < 4; ++nt) {
                const bf16x8 kb =
                    *(const bf16x8*)&Ks[nt * 16 + ln][kc * 32 + quad * 8];
                sacc[nt] = __builtin_amdgcn_mfma_f32_16x16x32_bf16(
                    qa[kc], kb, sacc[nt], 0, 0, 0);
            }
        }

        const bool fullv = (j < qt);
        float pv[4][4];
        float mt[4] = {-1e30f, -1e30f, -1e30f, -1e30f};
#pragma unroll
        for (int nt = 0; nt < 4; ++nt) {
            const bool mk = (Msk[nt * 16 + ln] != 0);
            const int kpos = j * 64 + nt * 16 + ln;
#pragma unroll
            for (int r = 0; r < 4; ++r) {
                float s = sacc[nt][r] * 0.125f;
                const bool valid =
                    mk && (fullv || kpos <= wrb + quad * 4 + r);
                s = valid ? s : -1e30f;
                pv[nt][r] = s;
                mt[r] = fmaxf(mt[r], s);
            }
        }
#pragma unroll
        for (int r = 0; r < 4; ++r) {
            mt[r] = fmaxf(mt[r], __shfl_xor(mt[r], 1));
            mt[r] = fmaxf(mt[r], __shfl_xor(mt[r], 2));
            mt[r] = fmaxf(mt[r], __shfl_xor(mt[r], 4));
            mt[r] = fmaxf(mt[r], __shfl_xor(mt[r], 8));
        }
        float alpha[4], rsum[4];
#pragma unroll
        for (int r = 0; r < 4; ++r) {
            const float mn = fmaxf(mrow[r], mt[r]);
            alpha[r] = __expf(mrow[r] - mn);
            mrow[r] = mn;
            rsum[r] = 0.f;
        }
#pragma unroll
        for (int nt = 0; nt < 4; ++nt)
#pragma unroll
            for (int r = 0; r < 4; ++r) {
                const float p = (pv[nt][r] <= -1e29f)
                                    ? 0.f
                                    : __expf(pv[nt][r] - mrow[r]);
                pv[nt][r] = p;
                rsum[r] += p;
            }
#pragma unroll
        for (int r = 0; r < 4; ++r) {
            rsum[r] += __shfl_xor(rsum[r], 1);
            rsum[r] += __shfl_xor(rsum[r], 2);
            rsum[r] += __shfl_xor(rsum[r], 4);
            rsum[r] += __shfl_xor(rsum[r], 8);
            lrow[r] = lrow[r] * alpha[r] + rsum[r];
        }
#pragma unroll
        for (int nt = 0; nt < 4; ++nt)
#pragma unroll
            for (int r = 0; r < 4; ++r) oacc[nt][r] *= alpha[r];

#pragma unroll
        for (int nt = 0; nt < 4; ++nt)
#pragma unroll
            for (int r = 0; r < 4; ++r)
                Ps[wave * 16 + quad * 4 + r][nt * 16 + ln] =
                    bf16rne(pv[nt][r]);
        asm volatile("s_waitcnt lgkmcnt(0)" ::: "memory");

#pragma unroll
        for (int kc = 0; kc < 2; ++kc) {
            const bf16x8 pa =
                *(const bf16x8*)&Ps[wave * 16 + ln][kc * 32 + quad * 8];
#pragma unroll
            for (int nt = 0; nt < 4; ++nt) {
                const bf16x8 vb =
                    *(const bf16x8*)&Vt[nt * 16 + ln][kc * 32 + quad * 8];
                oacc[nt] = __builtin_amdgcn_mfma_f32_16x16x32_bf16(
                    pa, vb, oacc[nt], 0, 0, 0);
            }
        }
    }

#pragma unroll
    for (int r = 0; r < 4; ++r) {
        const float inv = 1.0f / lrow[r];
        const size_t rowoff = ((size_t)b * Tn + wrb + quad * 4 + r) * Hn;
#pragma unroll
        for (int nt = 0; nt < 4; ++nt)
            out[rowoff + nt * 16 + ln] = oacc[nt][r] * inv;
    }
}

extern "C" void kernel_launch(void* const* d_in, const int* in_sizes, int n_in,
                              void* d_out, int out_size, void* d_ws, size_t ws_size,
                              hipStream_t stream)
{
    const float* k    = (const float*)d_in[0];
    const float* q    = (const float*)d_in[1];
    const float* v    = (const float*)d_in[2];
    const int*   mask = (const int*)d_in[3];
    const float* Wk   = (const float*)d_in[4];
    const float* Wq   = (const float*)d_in[5];
    const float* Wv   = (const float*)d_in[6];
    float* out = (float*)d_out;
    unsigned short* ws = (unsigned short*)d_ws;  // kh|qh|vh bf16 | Wb bf16

    wconv_kernel<<<dim3(192), dim3(256), 0, stream>>>(Wk, Wq, Wv,
                                                      ws + 3 * BTHb);

    dim3 pb(256), pg(Bn * Tn / 64, 3);
    proj_kernel<<<pg, pb, 0, stream>>>(k, q, v, ws);

    dim3 ab(256), ag(Tn / 64, Bn);
    attn_kernel<<<ag, ab, 0, stream>>>(ws, mask, out);
}

// Round 6
// 293.692 us; speedup vs baseline: 1.0160x; 1.0160x over previous
//
#include <hip/hip_runtime.h>
#include <hip/hip_bf16.h>
#include <math.h>

#define Bn 8
#define Tn 2048
#define Cn 1024
#define Hn 64
#define BTHb ((size_t)Bn * Tn * Hn)   // elements per projected matrix (bf16)
#define WELEMS ((size_t)Hn * Cn)      // 65536 elements per W matrix

typedef __attribute__((ext_vector_type(8))) short bf16x8;
typedef __attribute__((ext_vector_type(4))) float f32x4;

static __device__ __forceinline__ unsigned short bf16rne(float f) {
    union { float f; unsigned u; } x; x.f = f;
    return (unsigned short)((x.u + 0x7FFFu + ((x.u >> 16) & 1u)) >> 16);
}

// ---------------------------------------------------------------------------
// W pre-convert: Wk|Wq|Wv fp32 -> bf16 (ws + 3*BTHb). 49152 float4s total.
// ---------------------------------------------------------------------------
__global__ __launch_bounds__(256) void wconv_kernel(
    const float* __restrict__ Wk, const float* __restrict__ Wq,
    const float* __restrict__ Wv, unsigned short* __restrict__ dst)
{
    const int g = blockIdx.x * 256 + threadIdx.x;        // 0..49151
    const float* src = (g < 16384) ? Wk : (g < 32768) ? Wq : Wv;
    const int local = g & 16383;
    const float4 f = ((const float4*)src)[local];
    ushort4 u;
    u.x = bf16rne(f.x); u.y = bf16rne(f.y);
    u.z = bf16rne(f.z); u.w = bf16rne(f.w);
    ((ushort4*)dst)[g] = u;
}

// ---------------------------------------------------------------------------
// MFMA projection v4: O[row,h] = sum_c X[row,c] * W[h,c]
// grid (256, 3); block 256 = 4 waves; 64 rows x 64 h per block.
// Zero barriers, zero LDS. K-loop FULLY UNROLLED with macro so the X
// ping/pong buffers are only indexed by compile-time constants -> stay in
// VGPRs (R5's runtime pointer-swap demoted them to scratch: VGPR_Count=32).
// Per chunk: issue next-X HBM loads first (one full chunk of latency
// budget), convert current X regs to bf16, then L2-hot W loads + 16 MFMAs.
// ---------------------------------------------------------------------------
__global__ __launch_bounds__(256) void proj_kernel(
    const float* __restrict__ k, const float* __restrict__ q,
    const float* __restrict__ v,
    unsigned short* __restrict__ ws)
{
    const int which = blockIdx.y;
    const float* X = (which == 0) ? k : (which == 1) ? q : v;
    const unsigned short* Wsrc = ws + 3 * BTHb + (size_t)which * WELEMS;
    unsigned short* O = ws + (size_t)which * BTHb;

    const int tid  = threadIdx.x;
    const int wave = __builtin_amdgcn_readfirstlane(tid >> 6);
    const int lane = tid & 63;
    const int ln   = lane & 15;
    const int quad = lane >> 4;
    const int row0 = blockIdx.x * 64;

    const float* Xrow = X + (size_t)(row0 + wave * 16 + ln) * Cn + quad * 8;
    const unsigned short* Wrow0 = Wsrc + (size_t)(0 * 16 + ln) * Cn + quad * 8;
    const unsigned short* Wrow1 = Wsrc + (size_t)(1 * 16 + ln) * Cn + quad * 8;
    const unsigned short* Wrow2 = Wsrc + (size_t)(2 * 16 + ln) * Cn + quad * 8;
    const unsigned short* Wrow3 = Wsrc + (size_t)(3 * 16 + ln) * Cn + quad * 8;

    f32x4 acc[4];
#pragma unroll
    for (int t = 0; t < 4; ++t) acc[t] = (f32x4){0.f, 0.f, 0.f, 0.f};

    float4 x0[8], x1[8];   // only constant-indexed below -> SSA-promoted

    // prefetch chunk 0 into x0
#pragma unroll
    for (int kc = 0; kc < 4; ++kc) {
        x0[2 * kc]     = *(const float4*)(Xrow + kc * 32);
        x0[2 * kc + 1] = *(const float4*)(Xrow + kc * 32 + 4);
    }

#define PROJ_CHUNK(CT, CUR, NXT)                                              \
    {                                                                         \
        const int ctn = ((CT) + 1) & 7; /* wrap keeps last pf in-bounds */    \
        _Pragma("unroll")                                                     \
        for (int kc = 0; kc < 4; ++kc) {                                      \
            NXT[2 * kc]     = *(const float4*)(Xrow + ctn * 128 + kc * 32);   \
            NXT[2 * kc + 1] = *(const float4*)(Xrow + ctn * 128 + kc * 32 + 4);\
        }                                                                     \
        _Pragma("unroll")                                                     \
        for (int kc = 0; kc < 4; ++kc) {                                      \
            union { bf16x8 v; unsigned short s[8]; } u;                       \
            const float4 a = CUR[2 * kc], b = CUR[2 * kc + 1];                \
            u.s[0] = bf16rne(a.x); u.s[1] = bf16rne(a.y);                     \
            u.s[2] = bf16rne(a.z); u.s[3] = bf16rne(a.w);                     \
            u.s[4] = bf16rne(b.x); u.s[5] = bf16rne(b.y);                     \
            u.s[6] = bf16rne(b.z); u.s[7] = bf16rne(b.w);                     \
            const bf16x8 af = u.v;                                           \
            const int co = (CT) * 128 + kc * 32;                              \
            const bf16x8 w0 = *(const bf16x8*)(Wrow0 + co);                   \
            const bf16x8 w1 = *(const bf16x8*)(Wrow1 + co);                   \
            const bf16x8 w2 = *(const bf16x8*)(Wrow2 + co);                   \
            const bf16x8 w3 = *(const bf16x8*)(Wrow3 + co);                   \
            acc[0] = __builtin_amdgcn_mfma_f32_16x16x32_bf16(af, w0,          \
                                                             acc[0], 0, 0, 0);\
            acc[1] = __builtin_amdgcn_mfma_f32_16x16x32_bf16(af, w1,          \
                                                             acc[1], 0, 0, 0);\
            acc[2] = __builtin_amdgcn_mfma_f32_16x16x32_bf16(af, w2,          \
                                                             acc[2], 0, 0, 0);\
            acc[3] = __builtin_amdgcn_mfma_f32_16x16x32_bf16(af, w3,          \
                                                             acc[3], 0, 0, 0);\
        }                                                                     \
    }

    PROJ_CHUNK(0, x0, x1)
    PROJ_CHUNK(1, x1, x0)
    PROJ_CHUNK(2, x0, x1)
    PROJ_CHUNK(3, x1, x0)
    PROJ_CHUNK(4, x0, x1)
    PROJ_CHUNK(5, x1, x0)
    PROJ_CHUNK(6, x0, x1)
    PROJ_CHUNK(7, x1, x0)
#undef PROJ_CHUNK

    // D layout: col=lane&15, row=quad*4+reg
#pragma unroll
    for (int ht = 0; ht < 4; ++ht)
#pragma unroll
        for (int r = 0; r < 4; ++r)
            O[(size_t)(row0 + wave * 16 + quad * 4 + r) * Hn + ht * 16 + ln] =
                bf16rne(acc[ht][r]);
}

// ---------------------------------------------------------------------------
// MFMA flash attention (unchanged — validated). grid (32, 8);
// block 256 = 4 waves; 64-row q-tile per block; 64-key tiles.
// ---------------------------------------------------------------------------
__global__ __launch_bounds__(256) void attn_kernel(
    const unsigned short* __restrict__ ws,
    const int* __restrict__ mask,
    float* __restrict__ out)
{
    const unsigned short* kh = ws;
    const unsigned short* qh = ws + BTHb;
    const unsigned short* vh = ws + 2 * BTHb;

    const int b   = blockIdx.y;
    const int qt  = blockIdx.x;
    const int tid = threadIdx.x;
    const int wave = __builtin_amdgcn_readfirstlane(tid >> 6);
    const int lane = tid & 63;
    const int ln   = lane & 15;
    const int quad = lane >> 4;

    __shared__ unsigned short Ks[64][72];   // [kpos][dim]
    __shared__ unsigned short Vt[64][72];   // [dim][kpos]
    __shared__ unsigned short Ps[64][72];   // [q-row local][kpos]
    __shared__ int Msk[64];

    const int wrb = qt * 64 + wave * 16;

    bf16x8 qa[2];
#pragma unroll
    for (int kc = 0; kc < 2; ++kc)
        qa[kc] = *(const bf16x8*)(qh + ((size_t)b * Tn + wrb + ln) * Hn
                                     + kc * 32 + quad * 8);

    f32x4 oacc[4];
#pragma unroll
    for (int t = 0; t < 4; ++t) oacc[t] = (f32x4){0.f, 0.f, 0.f, 0.f};
    float mrow[4] = {-1e30f, -1e30f, -1e30f, -1e30f};
    float lrow[4] = {0.f, 0.f, 0.f, 0.f};

    const int krow = tid >> 2, kseg = tid & 3;
    const int vcol = tid & 63, vseg = tid >> 6;

    uint4 kreg[2], vreg[2];
    int mreg = 0;
    {
        const unsigned short* kp =
            kh + ((size_t)b * Tn + krow) * Hn + kseg * 16;
        kreg[0] = *(const uint4*)kp;
        kreg[1] = *(const uint4*)(kp + 8);
        const unsigned short* vp =
            vh + ((size_t)b * Tn + vcol) * Hn + vseg * 16;
        vreg[0] = *(const uint4*)vp;
        vreg[1] = *(const uint4*)(vp + 8);
        if (tid < 64) mreg = mask[(size_t)b * Tn + tid];
    }

    for (int j = 0; j <= qt; ++j) {
        __syncthreads();
        *(uint4*)&Ks[krow][kseg * 16]     = kreg[0];
        *(uint4*)&Ks[krow][kseg * 16 + 8] = kreg[1];
        {
            const unsigned short* vs = (const unsigned short*)vreg;
#pragma unroll
            for (int jj = 0; jj < 16; ++jj)
                Vt[vseg * 16 + jj][vcol] = vs[jj];
        }
        if (tid < 64) Msk[tid] = mreg;
        __syncthreads();

        if (j < qt) {
            const unsigned short* kp =
                kh + ((size_t)b * Tn + (j + 1) * 64 + krow) * Hn + kseg * 16;
            kreg[0] = *(const uint4*)kp;
            kreg[1] = *(const uint4*)(kp + 8);
            const unsigned short* vp =
                vh + ((size_t)b * Tn + (j + 1) * 64 + vcol) * Hn + vseg * 16;
            vreg[0] = *(const uint4*)vp;
            vreg[1] = *(const uint4*)(vp + 8);
            if (tid < 64) mreg = mask[(size_t)b * Tn + (j + 1) * 64 + tid];
        }

        f32x4 sacc[4];
#pragma unroll
        for (int t = 0; t < 4; ++t) sacc[t] = (f32x4){0.f, 0.f, 0.f, 0.f};
#pragma unroll
        for (int kc = 0; kc < 2; ++kc) {
#pragma unroll
            for (int nt = 0; nt < 4; ++nt) {
                const bf16x8 kb =
                    *(const bf16x8*)&Ks[nt * 16 + ln][kc * 32 + quad * 8];
                sacc[nt] = __builtin_amdgcn_mfma_f32_16x16x32_bf16(
                    qa[kc], kb, sacc[nt], 0, 0, 0);
            }
        }

        const bool fullv = (j < qt);
        float pv[4][4];
        float mt[4] = {-1e30f, -1e30f, -1e30f, -1e30f};
#pragma unroll
        for (int nt = 0; nt < 4; ++nt) {
            const bool mk = (Msk[nt * 16 + ln] != 0);
            const int kpos = j * 64 + nt * 16 + ln;
#pragma unroll
            for (int r = 0; r < 4; ++r) {
                float s = sacc[nt][r] * 0.125f;
                const bool valid =
                    mk && (fullv || kpos <= wrb + quad * 4 + r);
                s = valid ? s : -1e30f;
                pv[nt][r] = s;
                mt[r] = fmaxf(mt[r], s);
            }
        }
#pragma unroll
        for (int r = 0; r < 4; ++r) {
            mt[r] = fmaxf(mt[r], __shfl_xor(mt[r], 1));
            mt[r] = fmaxf(mt[r], __shfl_xor(mt[r], 2));
            mt[r] = fmaxf(mt[r], __shfl_xor(mt[r], 4));
            mt[r] = fmaxf(mt[r], __shfl_xor(mt[r], 8));
        }
        float alpha[4], rsum[4];
#pragma unroll
        for (int r = 0; r < 4; ++r) {
            const float mn = fmaxf(mrow[r], mt[r]);
            alpha[r] = __expf(mrow[r] - mn);
            mrow[r] = mn;
            rsum[r] = 0.f;
        }
#pragma unroll
        for (int nt = 0; nt < 4; ++nt)
#pragma unroll
            for (int r = 0; r < 4; ++r) {
                const float p = (pv[nt][r] <= -1e29f)
                                    ? 0.f
                                    : __expf(pv[nt][r] - mrow[r]);
                pv[nt][r] = p;
                rsum[r] += p;
            }
#pragma unroll
        for (int r = 0; r < 4; ++r) {
            rsum[r] += __shfl_xor(rsum[r], 1);
            rsum[r] += __shfl_xor(rsum[r], 2);
            rsum[r] += __shfl_xor(rsum[r], 4);
            rsum[r] += __shfl_xor(rsum[r], 8);
            lrow[r] = lrow[r] * alpha[r] + rsum[r];
        }
#pragma unroll
        for (int nt = 0; nt < 4; ++nt)
#pragma unroll
            for (int r = 0; r < 4; ++r) oacc[nt][r] *= alpha[r];

#pragma unroll
        for (int nt = 0; nt < 4; ++nt)
#pragma unroll
            for (int r = 0; r < 4; ++r)
                Ps[wave * 16 + quad * 4 + r][nt * 16 + ln] =
                    bf16rne(pv[nt][r]);
        asm volatile("s_waitcnt lgkmcnt(0)" ::: "memory");

#pragma unroll
        for (int kc = 0; kc < 2; ++kc) {
            const bf16x8 pa =
                *(const bf16x8*)&Ps[wave * 16 + ln][kc * 32 + quad * 8];
#pragma unroll
            for (int nt = 0; nt < 4; ++nt) {
                const bf16x8 vb =
                    *(const bf16x8*)&Vt[nt * 16 + ln][kc * 32 + quad * 8];
                oacc[nt] = __builtin_amdgcn_mfma_f32_16x16x32_bf16(
                    pa, vb, oacc[nt], 0, 0, 0);
            }
        }
    }

#pragma unroll
    for (int r = 0; r < 4; ++r) {
        const float inv = 1.0f / lrow[r];
        const size_t rowoff = ((size_t)b * Tn + wrb + quad * 4 + r) * Hn;
#pragma unroll
        for (int nt = 0; nt < 4; ++nt)
            out[rowoff + nt * 16 + ln] = oacc[nt][r] * inv;
    }
}

extern "C" void kernel_launch(void* const* d_in, const int* in_sizes, int n_in,
                              void* d_out, int out_size, void* d_ws, size_t ws_size,
                              hipStream_t stream)
{
    const float* k    = (const float*)d_in[0];
    const float* q    = (const float*)d_in[1];
    const float* v    = (const float*)d_in[2];
    const int*   mask = (const int*)d_in[3];
    const float* Wk   = (const float*)d_in[4];
    const float* Wq   = (const float*)d_in[5];
    const float* Wv   = (const float*)d_in[6];
    float* out = (float*)d_out;
    unsigned short* ws = (unsigned short*)d_ws;  // kh|qh|vh bf16 | Wb bf16

    wconv_kernel<<<dim3(192), dim3(256), 0, stream>>>(Wk, Wq, Wv,
                                                      ws + 3 * BTHb);

    dim3 pb(256), pg(Bn * Tn / 64, 3);
    proj_kernel<<<pg, pb, 0, stream>>>(k, q, v, ws);

    dim3 ab(256), ag(Tn / 64, Bn);
    attn_kernel<<<ag, ab, 0, stream>>>(ws, mask, out);
}